// Round 2
// baseline (130.392 us; speedup 1.0000x reference)
//
#include <hip/hip_runtime.h>
#include <math.h>

#define BB 32
#define HH 256
#define WW 256
#define HW (HH*WW)
#define K_BG 0.1f
#define RELAX 5.0f
#define EPS_D 1e-7
#define RPB 4                       // rows per k_mega block
#define MEGA_BLOCKS (BB * (HH / RPB))   // 2048

typedef unsigned long long u64;

__device__ __forceinline__ float sigf(float x) { return 1.0f / (1.0f + expf(-x)); }

__device__ __forceinline__ u64 shflx64(u64 x, int s) {
    return (u64)__shfl_xor((unsigned long long)x, s, 64);
}

// ---------------- dilation + transpose: column-major masks, ONCE per image ----
// 128 blocks = 32 images x 4 rowgroups of 64 rows. Each block:
//   ballot raw bits (rows r0-2 .. r0+65) -> horizontal +-2 dilate ->
//   vertical +-2 dilate -> 6-stage butterfly bit-transpose (once!) ->
//   colmask[b][g][col] : bits = rows 64g..64g+63 of dilated mask, column col.
// Also emits nzmask (raw target bits, row-major) and resets the tail ticket.
__global__ __launch_bounds__(512) void k_maskdil(const float* __restrict__ tg,
                                                 u64* __restrict__ colmask,
                                                 u64* __restrict__ nzmask,
                                                 unsigned* __restrict__ cnt) {
    __shared__ u64 nz[68][4];
    __shared__ u64 hd[68][4];
    __shared__ u64 dil[64][5];      // +1 pad: kills 16-way conflict on column read
    int blk = blockIdx.x;
    int b = blk >> 2, g = blk & 3;
    int r0 = g * 64;
    int tid = threadIdx.x;
    int col = tid & 255;
    int team = tid >> 8;            // 2 teams of 4 waves split the 68 row loads
    const float* img = tg + b * HW;
    if (blk == 0 && tid == 0) cnt[0] = 0;   // ticket reset before any k_mega runs

    const int RT = 34;              // rows per team
    int lr0 = team * RT;
    for (int base = 0; base < RT; base += 12) {   // 12 loads in flight per round
        float v[12];
        #pragma unroll
        for (int k = 0; k < 12; ++k) {
            int lr = lr0 + base + k;
            int rg = r0 - 2 + lr;
            v[k] = (base + k < RT && rg >= 0 && rg < HH) ? img[rg * WW + col] : 0.0f;
        }
        #pragma unroll
        for (int k = 0; k < 12; ++k) {
            if (base + k < RT) {
                u64 bal = __ballot(v[k] != 0.0f);
                if ((tid & 63) == 0) nz[lr0 + base + k][(tid >> 6) & 3] = bal;
            }
        }
    }
    __syncthreads();
    if (tid < 272) {                // 68 rows x 4 words: horizontal +-2 dilate
        int lr = tid >> 2, k = tid & 3;
        u64 m = nz[lr][k];
        u64 ml = (k > 0) ? nz[lr][k - 1] : 0ULL;
        u64 mr = (k < 3) ? nz[lr][k + 1] : 0ULL;
        hd[lr][k] = m | (m << 1) | (m << 2) | (m >> 1) | (m >> 2)
                  | (ml >> 62) | (ml >> 63) | (mr << 62) | (mr << 63);
    }
    if (tid < 256) {                // raw masks for the 64 owned rows
        int rr = tid >> 2, k = tid & 3;
        nzmask[b * 1024 + (r0 + rr) * 4 + k] = nz[rr + 2][k];
    }
    __syncthreads();
    if (tid < 256) {                // 64 rows x 4 words: vertical +-2 dilate
        int rr = tid >> 2, k = tid & 3;
        dil[rr][k] = hd[rr][k] | hd[rr + 1][k] | hd[rr + 2][k] | hd[rr + 3][k] | hd[rr + 4][k];
    }
    __syncthreads();
    if (tid < 256) {                // butterfly transpose: wave w owns word w
        int w = tid >> 6, lane = tid & 63;
        u64 x = dil[lane][w];       // row (64g+lane), word w
        const u64 L32 = 0x00000000FFFFFFFFULL, L16 = 0x0000FFFF0000FFFFULL,
                  L8  = 0x00FF00FF00FF00FFULL, L4  = 0x0F0F0F0F0F0F0F0FULL,
                  L2  = 0x3333333333333333ULL, L1  = 0x5555555555555555ULL;
        u64 pp;
        pp = shflx64(x, 32); x = (lane & 32) ? ((x & ~L32) | ((pp & ~L32) >> 32)) : ((x & L32) | ((pp & L32) << 32));
        pp = shflx64(x, 16); x = (lane & 16) ? ((x & ~L16) | ((pp & ~L16) >> 16)) : ((x & L16) | ((pp & L16) << 16));
        pp = shflx64(x,  8); x = (lane &  8) ? ((x & ~L8 ) | ((pp & ~L8 ) >>  8)) : ((x & L8 ) | ((pp & L8 ) <<  8));
        pp = shflx64(x,  4); x = (lane &  4) ? ((x & ~L4 ) | ((pp & ~L4 ) >>  4)) : ((x & L4 ) | ((pp & L4 ) <<  4));
        pp = shflx64(x,  2); x = (lane &  2) ? ((x & ~L2 ) | ((pp & ~L2 ) >>  2)) : ((x & L2 ) | ((pp & L2 ) <<  2));
        pp = shflx64(x,  1); x = (lane &  1) ? ((x & ~L1 ) | ((pp & ~L1 ) >>  1)) : ((x & L1 ) | ((pp & L1 ) <<  1));
        colmask[b * 1024 + g * 256 + w * 64 + lane] = x;   // column (64w+lane)
    }
}

// ---------------- mega: bit-parallel EDT + dice partials + fused tail ---------
// RPB=4 -> 2048 blocks -> 8 blocks/CU = 32 waves/CU (full occupancy; the R0
// profile showed k_mega latency-bound at 4 blocks/CU). Column masks come
// pre-transposed from k_maskdil: 4 coalesced u64 loads, no LDS colT, no
// butterfly, one fewer barrier. gS is f32 (no per-read cvt). Tail folded in
// via threadfence + last-block ticket (removes the 1-block k_tail launch).
__global__ __launch_bounds__(256, 8) void k_mega(const float* __restrict__ preds,
                                                 const u64* __restrict__ colmask,
                                                 const u64* __restrict__ nzmask,
                                                 float4* __restrict__ part1,
                                                 float4* __restrict__ part2,
                                                 unsigned* __restrict__ cnt,
                                                 float* __restrict__ out) {
    __shared__ float gS[RPB][WW];
    __shared__ float red[8][4];
    __shared__ unsigned stick;
    __shared__ float sI[BB], sC[BB], sA[BB];
    int blk = blockIdx.x;              // b*64 + q ; rows 4q..4q+3
    int b = blk >> 6, q = blk & 63;
    int i0 = q * RPB;
    int tid = threadIdx.x;
    int lane = tid & 63, wv = tid >> 6;
    int j = tid;                       // this thread's column

    float p[RPB];                      // issue HBM loads first; consumed much later
    #pragma unroll
    for (int rr = 0; rr < RPB; ++rr)
        p[rr] = preds[(b * HH + i0 + rr) * WW + j];
    u64 nzw[RPB];
    #pragma unroll
    for (int rr = 0; rr < RPB; ++rr)
        nzw[rr] = nzmask[b * 1024 + (i0 + rr) * 4 + wv];
    u64 yw[4];                         // set bit = zero pixel, column j
    #pragma unroll
    for (int g = 0; g < 4; ++g)
        yw[g] = ~colmask[b * 1024 + g * 256 + j];

    // ---- branchless vertical distance for RPB pixels (same column) ----
    int g0v[RPB], fgv[RPB];
    #pragma unroll
    for (int rr = 0; rr < RPB; ++rr) {
        int i = i0 + rr;
        int iw = i >> 6, ib = i & 63;
        u64 lowm  = (2ULL << ib) - 1ULL;          // bits 0..ib (ib=63 -> ~0)
        u64 highm = ~((1ULL << ib) - 1ULL);       // bits ib..63
        int pu = -1, pd = -1;
        #pragma unroll
        for (int w = 0; w < 4; ++w) {             // ascending: highest nonzero word wins
            u64 m = (w < iw) ? ~0ULL : ((w == iw) ? lowm : 0ULL);
            u64 z = yw[w] & m;
            int cand = (w << 6) + 63 - __clzll(z);
            pu = z ? cand : pu;
        }
        #pragma unroll
        for (int w = 3; w >= 0; --w) {            // descending: lowest nonzero word wins
            u64 m = (w > iw) ? ~0ULL : ((w == iw) ? highm : 0ULL);
            u64 z = yw[w] & m;
            int cand = (w << 6) + (__ffsll((unsigned long long)z) - 1);
            pd = z ? cand : pd;
        }
        int up = (pu >= 0) ? (i - pu) : 10000;
        int dn = (pd >= 0) ? (pd - i) : 10000;
        int g0 = min(min(up, dn), 10000);
        g0v[rr] = g0;
        fgv[rr] = (int)((~yw[iw] >> ib) & 1ULL);
        gS[rr][j] = (float)g0;
    }
    __syncthreads();

    // ---- min-plus walk (prefix + chunked tail) + dice partials ----
    float vals[8];
    #pragma unroll
    for (int qq = 0; qq < 6; ++qq) vals[qq] = 0.0f;
    vals[6] = 1e30f; vals[7] = 0.0f;
    #pragma unroll
    for (int rr = 0; rr < RPB; ++rr) {
        float gv = (float)g0v[rr];
        float best = gv * gv;
        #pragma unroll
        for (int r = 1; r <= 8; ++r) {            // branchless prefix
            float rf = (float)(r * r);
            int jl = j - r, jr = j + r;
            float vl = (jl >= 0) ? gS[rr][jl] : 1e4f;
            float vr = (jr < WW) ? gS[rr][jr] : 1e4f;
            best = fminf(best, fminf(fmaf(vl, vl, rf), fmaf(vr, vr, rf)));
        }
        for (int rc = 9; rc < WW + 8; rc += 8) {  // branchless 8-chunks, 1 test/chunk
            if ((float)(rc * rc) >= best) break;
            #pragma unroll
            for (int dr = 0; dr < 8; ++dr) {
                int r = rc + dr;
                float rf = (float)(r * r);
                int jl = j - r, jr = j + r;
                float vl = (jl >= 0) ? gS[rr][jl] : 1e4f;
                float vr = (jr < WW) ? gS[rr][jr] : 1e4f;
                best = fminf(best, fminf(fmaf(vl, vl, rf), fmaf(vr, vr, rf)));
            }
        }
        float dv = sqrtf(best);
        float sp = sigf(p[rr]);
        float sd = sigf(dv / RELAX);
        float tv = (float)((nzw[rr] >> (j & 63)) & 1ULL);
        vals[0] += sp * sd * tv;                  // A
        vals[1] += sp * tv;                       // B
        vals[2] += sp * sd;                       // A'
        vals[3] += sp;                            // B'
        vals[4] += fgv[rr] ? 0.0f : sp;           // C' = sp*(1-fat)
        vals[5] += tv;                            // T
        vals[6] = fminf(vals[6], dv);
        vals[7] = fmaxf(vals[7], dv);
    }
    for (int off = 32; off > 0; off >>= 1) {
        #pragma unroll
        for (int qq = 0; qq < 6; ++qq) vals[qq] += __shfl_down(vals[qq], off, 64);
        vals[6] = fminf(vals[6], __shfl_down(vals[6], off, 64));
        vals[7] = fmaxf(vals[7], __shfl_down(vals[7], off, 64));
    }
    if (lane == 0) {
        #pragma unroll
        for (int qq = 0; qq < 8; ++qq) red[qq][wv] = vals[qq];
    }
    __syncthreads();
    if (tid == 0) {
        float s[8];
        #pragma unroll
        for (int qq = 0; qq < 6; ++qq) s[qq] = red[qq][0] + red[qq][1] + red[qq][2] + red[qq][3];
        s[6] = fminf(fminf(red[6][0], red[6][1]), fminf(red[6][2], red[6][3]));
        s[7] = fmaxf(fmaxf(red[7][0], red[7][1]), fmaxf(red[7][2], red[7][3]));
        part1[blk] = make_float4(s[0], s[1], s[2], s[3]);
        part2[blk] = make_float4(s[4], s[5], s[6], s[7]);
        __threadfence();                          // release partials
        stick = atomicAdd(cnt, 1u);
    }
    __syncthreads();
    if (stick != MEGA_BLOCKS - 1) return;

    // ---- fused tail: last block folds 64 partials/image, final scalar ----
    __threadfence();                              // acquire partials
    #pragma unroll
    for (int pass = 0; pass < 8; ++pass) {
        int img = pass * 4 + wv;                  // 4 images per pass, 64 lanes each
        float4 p1 = part1[img * 64 + lane];
        float4 p2 = part2[img * 64 + lane];
        float v2[8] = {p1.x, p1.y, p1.z, p1.w, p2.x, p2.y, p2.z, p2.w};
        for (int off = 32; off > 0; off >>= 1) {
            #pragma unroll
            for (int qq = 0; qq < 6; ++qq) v2[qq] += __shfl_down(v2[qq], off, 64);
            v2[6] = fminf(v2[6], __shfl_down(v2[6], off, 64));
            v2[7] = fmaxf(v2[7], __shfl_down(v2[7], off, 64));
        }
        if (lane == 0) {
            float A = v2[0], Bs = v2[1], Ap = v2[2], Bp = v2[3];
            float Cp = v2[4], T = v2[5], dmn = v2[6], dmx = v2[7];
            float inter, card, any;
            if (dmx > 0.0f) {          // image has foreground
                float smin = sigf(dmn / RELAX);
                float smax = sigf(dmx / RELAX);
                float m = smax - smin;
                float denom = (m > 0.0f) ? m : 1.0f;
                inter = (A - smin * Bs) / denom;   // Σ sp·t·(1-fat) == 0 exactly
                card  = (Ap - smin * Bp) / denom + K_BG * Cp + T;
                any = 1.0f;
            } else {                   // dm = 1 - t ; t == 0 everywhere
                inter = 0.0f;
                card = Bp - Bs + T;
                any = 0.0f;
            }
            sI[img] = inter; sC[img] = card; sA[img] = any;
        }
    }
    __syncthreads();
    if (tid == 0) {
        double I = 0.0, C = 0.0;
        int any = 0;
        for (int bb = 0; bb < BB; ++bb) {
            I += (double)sI[bb]; C += (double)sC[bb];
            any |= (sA[bb] > 0.0f);
        }
        double dice = 2.0 * I / fmax(C, (double)EPS_D);
        out[0] = any ? (float)(1.0 - dice) : 0.0f;
    }
}

extern "C" void kernel_launch(void* const* d_in, const int* in_sizes, int n_in,
                              void* d_out, int out_size, void* d_ws, size_t ws_size,
                              hipStream_t stream) {
    const float* preds = (const float*)d_in[0];
    const float* tg    = (const float*)d_in[1];
    float* out = (float*)d_out;

    u64* colmask  = (u64*)d_ws;                      // 256 KB
    u64* nzmask   = colmask + BB * 1024;             // 256 KB
    float4* part1 = (float4*)(nzmask + BB * 1024);   // 32 KB, 16B-aligned
    float4* part2 = part1 + MEGA_BLOCKS;             // 32 KB
    unsigned* cnt = (unsigned*)(part2 + MEGA_BLOCKS);

    hipLaunchKernelGGL(k_maskdil, dim3(BB * 4), dim3(512), 0, stream,
                       tg, colmask, nzmask, cnt);
    hipLaunchKernelGGL(k_mega, dim3(MEGA_BLOCKS), dim3(WW), 0, stream,
                       preds, colmask, nzmask, part1, part2, cnt, out);
}

// Round 3
// 127.867 us; speedup vs baseline: 1.0197x; 1.0197x over previous
//
#include <hip/hip_runtime.h>
#include <math.h>

#define BB 32
#define HH 256
#define WW 256
#define HW (HH*WW)
#define K_BG 0.1f
#define RELAX 5.0f
#define EPS_D 1e-7
#define RPB 8                          // rows per k_mega block (R0-proven geometry)
#define MEGA_BLOCKS (BB * (HH / RPB))  // 1024 = 4 blocks/CU, all resident

typedef unsigned long long u64;

__device__ __forceinline__ float sigf(float x) { return 1.0f / (1.0f + expf(-x)); }

__device__ __forceinline__ u64 shflx64(u64 x, int s) {
    return (u64)__shfl_xor((unsigned long long)x, s, 64);
}

// ---------------- binary 5x5 dilation as bit-ops -> row masks ----------------
// R0-proven structure: 512 blocks x 256 threads (16-row bands, full GPU).
// dmaskT: dilated mask, WORD-MAJOR [b][word w][row]  (k_mega's transpose input)
// nzmask: raw target mask, row-major [b][row][word]
__global__ void k_maskdil(const float* __restrict__ tg, u64* __restrict__ dmaskT,
                          u64* __restrict__ nzmask, unsigned* __restrict__ cnt) {
    __shared__ u64 nz[20][4];
    __shared__ u64 hd[20][4];
    int blk = blockIdx.x;              // 32 images x 16 bands of 16 rows
    int b = blk >> 4, band = blk & 15;
    int r0 = band * 16;
    int t = threadIdx.x, w = t >> 6;
    const float* img = tg + b * HW;
    if (blk == 0 && t == 0) cnt[0] = 0;      // ticket reset before any k_mega runs
    float v[20];
    #pragma unroll
    for (int rr = 0; rr < 20; ++rr) {  // all loads issued first: one HBM latency
        int rg = r0 + rr - 2;
        v[rr] = (rg >= 0 && rg < HH) ? img[rg * WW + t] : 0.0f;
    }
    #pragma unroll
    for (int rr = 0; rr < 20; ++rr) {
        u64 bal = __ballot(v[rr] != 0.0f);
        if ((t & 63) == 0) nz[rr][w] = bal;
    }
    __syncthreads();
    if (t < 80) {                      // 20 rows x 4 words: horizontal +-2 dilate
        int rr = t >> 2, k = t & 3;
        u64 m = nz[rr][k];
        u64 ml = (k > 0) ? nz[rr][k - 1] : 0ULL;
        u64 mr = (k < 3) ? nz[rr][k + 1] : 0ULL;
        hd[rr][k] = m | (m << 1) | (m << 2) | (m >> 1) | (m >> 2)
                  | (ml >> 62) | (ml >> 63) | (mr << 62) | (mr << 63);
    }
    if (t < 64) {                      // raw masks for the 16 owned rows
        int rr = t >> 2, k = t & 3;
        nzmask[b * 1024 + (r0 + rr) * 4 + k] = nz[rr + 2][k];
    }
    __syncthreads();
    if (t < 64) {                      // 16 rows x 4 words: vertical +-2 dilate
        int rr = t >> 2, k = t & 3;
        u64 o = hd[rr][k] | hd[rr + 1][k] | hd[rr + 2][k] | hd[rr + 3][k] | hd[rr + 4][k];
        dmaskT[b * 1024 + k * 256 + (r0 + rr)] = o;   // word-major
    }
}

// ---------------- mega: transpose + bit-parallel EDT + dice + fused tail ------
// R2 post-mortem: stall-bound (VALUBusy 22%), NOT occupancy-bound. Fix is ILP:
//  - prefix walk with r OUTER, rows INNER -> 8 independent fmin chains,
//    128 independent LDS reads (was: 8 serial chains split by dynamic loops)
//  - rare chunk loops hoisted to a second pass (fat distances <= ~4, so the
//    rc=9 test breaks immediately for ~97% of wave-rows)
//  - sqrt/sigmoid/accumulate as one clean unrolled block over all 8 rows
// Geometry reverted to R0-proven 1024 blocks / RPB=8 / in-block butterfly.
// Kept from R2: f32 gS (no per-read cvt), fused ticket tail (no k_tail launch).
__global__ __launch_bounds__(256, 4) void k_mega(const float* __restrict__ preds,
                                                 const u64* __restrict__ dmaskT,
                                                 const u64* __restrict__ nzmask,
                                                 float4* __restrict__ part1,
                                                 float4* __restrict__ part2,
                                                 unsigned* __restrict__ cnt,
                                                 float* __restrict__ out) {
    __shared__ u64 colT[4 * 256];      // [rowgroup g][col] : bits = rows 64g..64g+63
    __shared__ float gS[RPB][WW];
    __shared__ float red[8][4];
    __shared__ unsigned stick;
    __shared__ float sI[BB], sC[BB], sA[BB];
    int blk = blockIdx.x;              // b*32 + q ; rows 8q..8q+7
    int b = blk >> 5, q = blk & 31;
    int i0 = q * RPB;
    int tid = threadIdx.x;
    int lane = tid & 63, wv = tid >> 6;
    int j = tid;                       // this thread's column

    float p[RPB];                      // issue HBM loads first; consumed much later
    #pragma unroll
    for (int rr = 0; rr < RPB; ++rr)
        p[rr] = preds[(b * HH + i0 + rr) * WW + j];
    u64 nzw[RPB];
    #pragma unroll
    for (int rr = 0; rr < RPB; ++rr)
        nzw[rr] = nzmask[b * 1024 + (i0 + rr) * 4 + wv];

    // ---- register bit-transpose: wave wv owns row-group wv ----
    const u64* base = dmaskT + b * 1024;
    const u64 L32 = 0x00000000FFFFFFFFULL, L16 = 0x0000FFFF0000FFFFULL,
              L8  = 0x00FF00FF00FF00FFULL, L4  = 0x0F0F0F0F0F0F0F0FULL,
              L2  = 0x3333333333333333ULL, L1  = 0x5555555555555555ULL;
    #pragma unroll
    for (int w = 0; w < 4; ++w) {
        u64 x = base[w * 256 + wv * 64 + lane];   // row (64wv+lane), word w
        u64 pp;
        pp = shflx64(x, 32); x = (lane & 32) ? ((x & ~L32) | ((pp & ~L32) >> 32)) : ((x & L32) | ((pp & L32) << 32));
        pp = shflx64(x, 16); x = (lane & 16) ? ((x & ~L16) | ((pp & ~L16) >> 16)) : ((x & L16) | ((pp & L16) << 16));
        pp = shflx64(x,  8); x = (lane &  8) ? ((x & ~L8 ) | ((pp & ~L8 ) >>  8)) : ((x & L8 ) | ((pp & L8 ) <<  8));
        pp = shflx64(x,  4); x = (lane &  4) ? ((x & ~L4 ) | ((pp & ~L4 ) >>  4)) : ((x & L4 ) | ((pp & L4 ) <<  4));
        pp = shflx64(x,  2); x = (lane &  2) ? ((x & ~L2 ) | ((pp & ~L2 ) >>  2)) : ((x & L2 ) | ((pp & L2 ) <<  2));
        pp = shflx64(x,  1); x = (lane &  1) ? ((x & ~L1 ) | ((pp & ~L1 ) >>  1)) : ((x & L1 ) | ((pp & L1 ) <<  1));
        colT[wv * 256 + w * 64 + lane] = x;       // column (64w+lane), row-group wv
    }
    __syncthreads();

    u64 yw[4];                         // set bit = zero pixel, column j
    #pragma unroll
    for (int g = 0; g < 4; ++g) yw[g] = ~colT[g * 256 + j];

    // ---- branchless vertical distance for RPB pixels (same column) ----
    int g0v[RPB], fgv[RPB];
    #pragma unroll
    for (int rr = 0; rr < RPB; ++rr) {
        int i = i0 + rr;
        int iw = i >> 6, ib = i & 63;
        u64 lowm  = (2ULL << ib) - 1ULL;          // bits 0..ib (ib=63 -> ~0)
        u64 highm = ~((1ULL << ib) - 1ULL);       // bits ib..63
        int pu = -1, pd = -1;
        #pragma unroll
        for (int w = 0; w < 4; ++w) {             // ascending: highest nonzero word wins
            u64 m = (w < iw) ? ~0ULL : ((w == iw) ? lowm : 0ULL);
            u64 z = yw[w] & m;
            int cand = (w << 6) + 63 - __clzll(z);
            pu = z ? cand : pu;
        }
        #pragma unroll
        for (int w = 3; w >= 0; --w) {            // descending: lowest nonzero word wins
            u64 m = (w > iw) ? ~0ULL : ((w == iw) ? highm : 0ULL);
            u64 z = yw[w] & m;
            int cand = (w << 6) + (__ffsll((unsigned long long)z) - 1);
            pd = z ? cand : pd;
        }
        int up = (pu >= 0) ? (i - pu) : 10000;
        int dn = (pd >= 0) ? (pd - i) : 10000;
        int g0 = min(min(up, dn), 10000);
        g0v[rr] = g0;
        fgv[rr] = (int)((~yw[iw] >> ib) & 1ULL);
        gS[rr][j] = (float)g0;
    }
    __syncthreads();

    // ---- min-plus prefix: r OUTER, rows INNER -> 8 independent chains ----
    float best[RPB];
    #pragma unroll
    for (int rr = 0; rr < RPB; ++rr) {
        float gv = (float)g0v[rr];
        best[rr] = gv * gv;
    }
    #pragma unroll
    for (int r = 1; r <= 8; ++r) {
        float rf = (float)(r * r);
        int jl = j - r, jr = j + r;
        bool okl = (jl >= 0), okr = (jr < WW);
        #pragma unroll
        for (int rr = 0; rr < RPB; ++rr) {
            float vl = okl ? gS[rr][jl] : 1e4f;
            float vr = okr ? gS[rr][jr] : 1e4f;
            best[rr] = fminf(best[rr], fminf(fmaf(vl, vl, rf), fmaf(vr, vr, rf)));
        }
    }
    // ---- rare long-distance tail: exact, same semantics as reference ----
    #pragma unroll
    for (int rr = 0; rr < RPB; ++rr) {
        for (int rc = 9; rc < WW + 8; rc += 8) {  // branchless 8-chunks, 1 test/chunk
            if ((float)(rc * rc) >= best[rr]) break;
            #pragma unroll
            for (int dr = 0; dr < 8; ++dr) {
                int r = rc + dr;
                float rf = (float)(r * r);
                int jl = j - r, jr = j + r;
                float vl = (jl >= 0) ? gS[rr][jl] : 1e4f;
                float vr = (jr < WW) ? gS[rr][jr] : 1e4f;
                best[rr] = fminf(best[rr], fminf(fmaf(vl, vl, rf), fmaf(vr, vr, rf)));
            }
        }
    }

    // ---- accumulate phase: all rows unrolled together (ILP) ----
    float vals[8];
    #pragma unroll
    for (int qq = 0; qq < 6; ++qq) vals[qq] = 0.0f;
    vals[6] = 1e30f; vals[7] = 0.0f;
    #pragma unroll
    for (int rr = 0; rr < RPB; ++rr) {
        float dv = sqrtf(best[rr]);
        float sp = sigf(p[rr]);
        float sd = sigf(dv / RELAX);
        float tv = (float)((nzw[rr] >> (j & 63)) & 1ULL);
        vals[0] += sp * sd * tv;                  // A
        vals[1] += sp * tv;                       // B
        vals[2] += sp * sd;                       // A'
        vals[3] += sp;                            // B'
        vals[4] += fgv[rr] ? 0.0f : sp;           // C' = sp*(1-fat)
        vals[5] += tv;                            // T
        vals[6] = fminf(vals[6], dv);
        vals[7] = fmaxf(vals[7], dv);
    }
    for (int off = 32; off > 0; off >>= 1) {
        #pragma unroll
        for (int qq = 0; qq < 6; ++qq) vals[qq] += __shfl_down(vals[qq], off, 64);
        vals[6] = fminf(vals[6], __shfl_down(vals[6], off, 64));
        vals[7] = fmaxf(vals[7], __shfl_down(vals[7], off, 64));
    }
    if (lane == 0) {
        #pragma unroll
        for (int qq = 0; qq < 8; ++qq) red[qq][wv] = vals[qq];
    }
    __syncthreads();
    if (tid == 0) {
        float s[8];
        #pragma unroll
        for (int qq = 0; qq < 6; ++qq) s[qq] = red[qq][0] + red[qq][1] + red[qq][2] + red[qq][3];
        s[6] = fminf(fminf(red[6][0], red[6][1]), fminf(red[6][2], red[6][3]));
        s[7] = fmaxf(fmaxf(red[7][0], red[7][1]), fmaxf(red[7][2], red[7][3]));
        part1[blk] = make_float4(s[0], s[1], s[2], s[3]);
        part2[blk] = make_float4(s[4], s[5], s[6], s[7]);
        __threadfence();                          // release partials
        stick = atomicAdd(cnt, 1u);
    }
    __syncthreads();
    if (stick != MEGA_BLOCKS - 1) return;

    // ---- fused tail: last block folds 32 partials/image, final scalar ----
    __threadfence();                              // acquire partials
    #pragma unroll
    for (int pass = 0; pass < 4; ++pass) {
        int img = pass * 8 + (tid >> 5);          // 8 images per pass, 32 lanes each
        int k = tid & 31;
        float4 p1 = part1[img * 32 + k];
        float4 p2 = part2[img * 32 + k];
        float v2[8] = {p1.x, p1.y, p1.z, p1.w, p2.x, p2.y, p2.z, p2.w};
        for (int off = 16; off > 0; off >>= 1) {
            #pragma unroll
            for (int qq = 0; qq < 6; ++qq) v2[qq] += __shfl_down(v2[qq], off, 32);
            v2[6] = fminf(v2[6], __shfl_down(v2[6], off, 32));
            v2[7] = fmaxf(v2[7], __shfl_down(v2[7], off, 32));
        }
        if (k == 0) {
            float A = v2[0], Bs = v2[1], Ap = v2[2], Bp = v2[3];
            float Cp = v2[4], T = v2[5], dmn = v2[6], dmx = v2[7];
            float inter, card, any;
            if (dmx > 0.0f) {          // image has foreground
                float smin = sigf(dmn / RELAX);
                float smax = sigf(dmx / RELAX);
                float m = smax - smin;
                float denom = (m > 0.0f) ? m : 1.0f;
                inter = (A - smin * Bs) / denom;   // Σ sp·t·(1-fat) == 0 exactly
                card  = (Ap - smin * Bp) / denom + K_BG * Cp + T;
                any = 1.0f;
            } else {                   // dm = 1 - t ; t == 0 everywhere
                inter = 0.0f;
                card = Bp - Bs + T;
                any = 0.0f;
            }
            sI[img] = inter; sC[img] = card; sA[img] = any;
        }
    }
    __syncthreads();
    if (tid == 0) {
        double I = 0.0, C = 0.0;
        int any = 0;
        for (int bb = 0; bb < BB; ++bb) {
            I += (double)sI[bb]; C += (double)sC[bb];
            any |= (sA[bb] > 0.0f);
        }
        double dice = 2.0 * I / fmax(C, (double)EPS_D);
        out[0] = any ? (float)(1.0 - dice) : 0.0f;
    }
}

extern "C" void kernel_launch(void* const* d_in, const int* in_sizes, int n_in,
                              void* d_out, int out_size, void* d_ws, size_t ws_size,
                              hipStream_t stream) {
    const float* preds = (const float*)d_in[0];
    const float* tg    = (const float*)d_in[1];
    float* out = (float*)d_out;

    u64* dmaskT   = (u64*)d_ws;                      // 256 KB
    u64* nzmask   = dmaskT + BB * 1024;              // 256 KB
    float4* part1 = (float4*)(nzmask + BB * 1024);   // 16 KB, 16B-aligned
    float4* part2 = part1 + MEGA_BLOCKS;             // 16 KB
    unsigned* cnt = (unsigned*)(part2 + MEGA_BLOCKS);

    hipLaunchKernelGGL(k_maskdil, dim3(BB * 16), dim3(WW), 0, stream,
                       tg, dmaskT, nzmask, cnt);
    hipLaunchKernelGGL(k_mega, dim3(MEGA_BLOCKS), dim3(WW), 0, stream,
                       preds, dmaskT, nzmask, part1, part2, cnt, out);
}

// Round 5
// 104.001 us; speedup vs baseline: 1.2538x; 1.2295x over previous
//
#include <hip/hip_runtime.h>
#include <math.h>

#define BB 32
#define HH 256
#define WW 256
#define HW (HH*WW)
#define K_BG 0.1f
#define RELAX 5.0f
#define EPS_D 1e-7
#define RPB 8                          // rows per k_mega block (R0-proven geometry)
#define MEGA_BLOCKS (BB * (HH / RPB))  // 1024 = 4 blocks/CU

typedef unsigned long long u64;

__device__ __forceinline__ float sigf(float x) { return 1.0f / (1.0f + expf(-x)); }

__device__ __forceinline__ u64 shflx64(u64 x, int s) {
    return (u64)__shfl_xor((unsigned long long)x, s, 64);
}

// ---------------- binary 5x5 dilation as bit-ops -> row masks ----------------
// R0-proven structure: 512 blocks x 256 threads (16-row bands, full GPU).
// dmaskT: dilated mask, WORD-MAJOR [b][word w][row]  (k_mega's transpose input)
// nzmask: raw target mask, row-major [b][row][word]
__global__ void k_maskdil(const float* __restrict__ tg, u64* __restrict__ dmaskT,
                          u64* __restrict__ nzmask, unsigned* __restrict__ cnt) {
    __shared__ u64 nz[20][4];
    __shared__ u64 hd[20][4];
    int blk = blockIdx.x;              // 32 images x 16 bands of 16 rows
    int b = blk >> 4, band = blk & 15;
    int r0 = band * 16;
    int t = threadIdx.x, w = t >> 6;
    const float* img = tg + b * HW;
    if (blk == 0 && t == 0) cnt[0] = 0;      // ticket reset before any k_mega runs
    float v[20];
    #pragma unroll
    for (int rr = 0; rr < 20; ++rr) {  // all loads issued first: one HBM latency
        int rg = r0 + rr - 2;
        v[rr] = (rg >= 0 && rg < HH) ? img[rg * WW + t] : 0.0f;
    }
    #pragma unroll
    for (int rr = 0; rr < 20; ++rr) {
        u64 bal = __ballot(v[rr] != 0.0f);
        if ((t & 63) == 0) nz[rr][w] = bal;
    }
    __syncthreads();
    if (t < 80) {                      // 20 rows x 4 words: horizontal +-2 dilate
        int rr = t >> 2, k = t & 3;
        u64 m = nz[rr][k];
        u64 ml = (k > 0) ? nz[rr][k - 1] : 0ULL;
        u64 mr = (k < 3) ? nz[rr][k + 1] : 0ULL;
        hd[rr][k] = m | (m << 1) | (m << 2) | (m >> 1) | (m >> 2)
                  | (ml >> 62) | (ml >> 63) | (mr << 62) | (mr << 63);
    }
    if (t < 64) {                      // raw masks for the 16 owned rows
        int rr = t >> 2, k = t & 3;
        nzmask[b * 1024 + (r0 + rr) * 4 + k] = nz[rr + 2][k];
    }
    __syncthreads();
    if (t < 64) {                      // 16 rows x 4 words: vertical +-2 dilate
        int rr = t >> 2, k = t & 3;
        u64 o = hd[rr][k] | hd[rr + 1][k] | hd[rr + 2][k] | hd[rr + 3][k] | hd[rr + 4][k];
        dmaskT[b * 1024 + k * 256 + (r0 + rr)] = o;   // word-major
    }
}

// ---------------- mega: transpose + bit-parallel EDT + dice + fused tail ------
// Assembly of ONLY proven components (R4 post-mortem):
//  - R0's row-at-a-time walk (47.6us, VGPR 36, zero spills) -- both attempted
//    restructures regressed (R2: occupancy halving; R3: spills, WRITE 46MB)
//  - f32 gS (R2/R3-proven, removes per-read cvt)
//  - fused ticket tail at 1024 blocks (R3-proven correct, absmax 0.0)
__global__ __launch_bounds__(256, 4) void k_mega(const float* __restrict__ preds,
                                                 const u64* __restrict__ dmaskT,
                                                 const u64* __restrict__ nzmask,
                                                 float4* __restrict__ part1,
                                                 float4* __restrict__ part2,
                                                 unsigned* __restrict__ cnt,
                                                 float* __restrict__ out) {
    __shared__ u64 colT[4 * 256];      // [rowgroup g][col] : bits = rows 64g..64g+63
    __shared__ float gS[RPB][WW];
    __shared__ float red[8][4];
    __shared__ unsigned stick;
    __shared__ float sI[BB], sC[BB], sA[BB];
    int blk = blockIdx.x;              // b*32 + q ; rows 8q..8q+7
    int b = blk >> 5, q = blk & 31;
    int i0 = q * RPB;
    int tid = threadIdx.x;
    int lane = tid & 63, wv = tid >> 6;
    int j = tid;                       // this thread's column

    float p[RPB];                      // issue HBM loads first; consumed much later
    #pragma unroll
    for (int rr = 0; rr < RPB; ++rr)
        p[rr] = preds[(b * HH + i0 + rr) * WW + j];
    u64 nzw[RPB];
    #pragma unroll
    for (int rr = 0; rr < RPB; ++rr)
        nzw[rr] = nzmask[b * 1024 + (i0 + rr) * 4 + wv];

    // ---- register bit-transpose: wave wv owns row-group wv ----
    const u64* base = dmaskT + b * 1024;
    const u64 L32 = 0x00000000FFFFFFFFULL, L16 = 0x0000FFFF0000FFFFULL,
              L8  = 0x00FF00FF00FF00FFULL, L4  = 0x0F0F0F0F0F0F0F0FULL,
              L2  = 0x3333333333333333ULL, L1  = 0x5555555555555555ULL;
    #pragma unroll
    for (int w = 0; w < 4; ++w) {
        u64 x = base[w * 256 + wv * 64 + lane];   // row (64wv+lane), word w
        u64 pp;
        pp = shflx64(x, 32); x = (lane & 32) ? ((x & ~L32) | ((pp & ~L32) >> 32)) : ((x & L32) | ((pp & L32) << 32));
        pp = shflx64(x, 16); x = (lane & 16) ? ((x & ~L16) | ((pp & ~L16) >> 16)) : ((x & L16) | ((pp & L16) << 16));
        pp = shflx64(x,  8); x = (lane &  8) ? ((x & ~L8 ) | ((pp & ~L8 ) >>  8)) : ((x & L8 ) | ((pp & L8 ) <<  8));
        pp = shflx64(x,  4); x = (lane &  4) ? ((x & ~L4 ) | ((pp & ~L4 ) >>  4)) : ((x & L4 ) | ((pp & L4 ) <<  4));
        pp = shflx64(x,  2); x = (lane &  2) ? ((x & ~L2 ) | ((pp & ~L2 ) >>  2)) : ((x & L2 ) | ((pp & L2 ) <<  2));
        pp = shflx64(x,  1); x = (lane &  1) ? ((x & ~L1 ) | ((pp & ~L1 ) >>  1)) : ((x & L1 ) | ((pp & L1 ) <<  1));
        colT[wv * 256 + w * 64 + lane] = x;       // column (64w+lane), row-group wv
    }
    __syncthreads();

    u64 yw[4];                         // set bit = zero pixel, column j
    #pragma unroll
    for (int g = 0; g < 4; ++g) yw[g] = ~colT[g * 256 + j];

    // ---- branchless vertical distance for RPB pixels (same column) ----
    int g0v[RPB], fgv[RPB];
    #pragma unroll
    for (int rr = 0; rr < RPB; ++rr) {
        int i = i0 + rr;
        int iw = i >> 6, ib = i & 63;
        u64 lowm  = (2ULL << ib) - 1ULL;          // bits 0..ib (ib=63 -> ~0)
        u64 highm = ~((1ULL << ib) - 1ULL);       // bits ib..63
        int pu = -1, pd = -1;
        #pragma unroll
        for (int w = 0; w < 4; ++w) {             // ascending: highest nonzero word wins
            u64 m = (w < iw) ? ~0ULL : ((w == iw) ? lowm : 0ULL);
            u64 z = yw[w] & m;
            int cand = (w << 6) + 63 - __clzll(z);
            pu = z ? cand : pu;
        }
        #pragma unroll
        for (int w = 3; w >= 0; --w) {            // descending: lowest nonzero word wins
            u64 m = (w > iw) ? ~0ULL : ((w == iw) ? highm : 0ULL);
            u64 z = yw[w] & m;
            int cand = (w << 6) + (__ffsll((unsigned long long)z) - 1);
            pd = z ? cand : pd;
        }
        int up = (pu >= 0) ? (i - pu) : 10000;
        int dn = (pd >= 0) ? (pd - i) : 10000;
        int g0 = min(min(up, dn), 10000);
        g0v[rr] = g0;
        fgv[rr] = (int)((~yw[iw] >> ib) & 1ULL);
        gS[rr][j] = (float)g0;
    }
    __syncthreads();

    // ---- R0's row-at-a-time min-plus walk + dice partials ----
    float vals[8];
    #pragma unroll
    for (int qq = 0; qq < 6; ++qq) vals[qq] = 0.0f;
    vals[6] = 1e30f; vals[7] = 0.0f;
    #pragma unroll
    for (int rr = 0; rr < RPB; ++rr) {
        float gv = (float)g0v[rr];
        float best = gv * gv;
        #pragma unroll
        for (int r = 1; r <= 8; ++r) {            // branchless prefix
            float rf = (float)(r * r);
            int jl = j - r, jr = j + r;
            float vl = (jl >= 0) ? gS[rr][jl] : 1e4f;
            float vr = (jr < WW) ? gS[rr][jr] : 1e4f;
            best = fminf(best, fminf(fmaf(vl, vl, rf), fmaf(vr, vr, rf)));
        }
        for (int rc = 9; rc < WW + 8; rc += 8) {  // branchless 8-chunks, 1 test/chunk
            if ((float)(rc * rc) >= best) break;
            #pragma unroll
            for (int dr = 0; dr < 8; ++dr) {
                int r = rc + dr;
                float rf = (float)(r * r);
                int jl = j - r, jr = j + r;
                float vl = (jl >= 0) ? gS[rr][jl] : 1e4f;
                float vr = (jr < WW) ? gS[rr][jr] : 1e4f;
                best = fminf(best, fminf(fmaf(vl, vl, rf), fmaf(vr, vr, rf)));
            }
        }
        float dv = sqrtf(best);
        float sp = sigf(p[rr]);
        float sd = sigf(dv / RELAX);
        float tv = (float)((nzw[rr] >> (j & 63)) & 1ULL);
        vals[0] += sp * sd * tv;                  // A
        vals[1] += sp * tv;                       // B
        vals[2] += sp * sd;                       // A'
        vals[3] += sp;                            // B'
        vals[4] += fgv[rr] ? 0.0f : sp;           // C' = sp*(1-fat)
        vals[5] += tv;                            // T
        vals[6] = fminf(vals[6], dv);
        vals[7] = fmaxf(vals[7], dv);
    }
    for (int off = 32; off > 0; off >>= 1) {
        #pragma unroll
        for (int qq = 0; qq < 6; ++qq) vals[qq] += __shfl_down(vals[qq], off, 64);
        vals[6] = fminf(vals[6], __shfl_down(vals[6], off, 64));
        vals[7] = fmaxf(vals[7], __shfl_down(vals[7], off, 64));
    }
    if (lane == 0) {
        #pragma unroll
        for (int qq = 0; qq < 8; ++qq) red[qq][wv] = vals[qq];
    }
    __syncthreads();
    if (tid == 0) {
        float s[8];
        #pragma unroll
        for (int qq = 0; qq < 6; ++qq) s[qq] = red[qq][0] + red[qq][1] + red[qq][2] + red[qq][3];
        s[6] = fminf(fminf(red[6][0], red[6][1]), fminf(red[6][2], red[6][3]));
        s[7] = fmaxf(fmaxf(red[7][0], red[7][1]), fmaxf(red[7][2], red[7][3]));
        part1[blk] = make_float4(s[0], s[1], s[2], s[3]);
        part2[blk] = make_float4(s[4], s[5], s[6], s[7]);
        __threadfence();                          // release partials
        stick = atomicAdd(cnt, 1u);
    }
    __syncthreads();
    if (stick != MEGA_BLOCKS - 1) return;

    // ---- fused tail: last block folds 32 partials/image (R3-proven) ----
    __threadfence();                              // acquire partials
    #pragma unroll
    for (int pass = 0; pass < 4; ++pass) {
        int img = pass * 8 + (tid >> 5);          // 8 images per pass, 32 lanes each
        int k = tid & 31;
        float4 p1 = part1[img * 32 + k];
        float4 p2 = part2[img * 32 + k];
        float v2[8] = {p1.x, p1.y, p1.z, p1.w, p2.x, p2.y, p2.z, p2.w};
        for (int off = 16; off > 0; off >>= 1) {
            #pragma unroll
            for (int qq = 0; qq < 6; ++qq) v2[qq] += __shfl_down(v2[qq], off, 32);
            v2[6] = fminf(v2[6], __shfl_down(v2[6], off, 32));
            v2[7] = fmaxf(v2[7], __shfl_down(v2[7], off, 32));
        }
        if (k == 0) {
            float A = v2[0], Bs = v2[1], Ap = v2[2], Bp = v2[3];
            float Cp = v2[4], T = v2[5], dmn = v2[6], dmx = v2[7];
            float inter, card, any;
            if (dmx > 0.0f) {          // image has foreground
                float smin = sigf(dmn / RELAX);
                float smax = sigf(dmx / RELAX);
                float m = smax - smin;
                float denom = (m > 0.0f) ? m : 1.0f;
                inter = (A - smin * Bs) / denom;   // Σ sp·t·(1-fat) == 0 exactly
                card  = (Ap - smin * Bp) / denom + K_BG * Cp + T;
                any = 1.0f;
            } else {                   // dm = 1 - t ; t == 0 everywhere
                inter = 0.0f;
                card = Bp - Bs + T;
                any = 0.0f;
            }
            sI[img] = inter; sC[img] = card; sA[img] = any;
        }
    }
    __syncthreads();
    if (tid == 0) {
        double I = 0.0, C = 0.0;
        int any = 0;
        for (int bb = 0; bb < BB; ++bb) {
            I += (double)sI[bb]; C += (double)sC[bb];
            any |= (sA[bb] > 0.0f);
        }
        double dice = 2.0 * I / fmax(C, (double)EPS_D);
        out[0] = any ? (float)(1.0 - dice) : 0.0f;
    }
}

extern "C" void kernel_launch(void* const* d_in, const int* in_sizes, int n_in,
                              void* d_out, int out_size, void* d_ws, size_t ws_size,
                              hipStream_t stream) {
    const float* preds = (const float*)d_in[0];
    const float* tg    = (const float*)d_in[1];
    float* out = (float*)d_out;

    u64* dmaskT   = (u64*)d_ws;                      // 256 KB
    u64* nzmask   = dmaskT + BB * 1024;              // 256 KB
    float4* part1 = (float4*)(nzmask + BB * 1024);   // 16 KB, 16B-aligned
    float4* part2 = part1 + MEGA_BLOCKS;             // 16 KB
    unsigned* cnt = (unsigned*)(part2 + MEGA_BLOCKS);

    hipLaunchKernelGGL(k_maskdil, dim3(BB * 16), dim3(WW), 0, stream,
                       tg, dmaskT, nzmask, cnt);
    hipLaunchKernelGGL(k_mega, dim3(MEGA_BLOCKS), dim3(WW), 0, stream,
                       preds, dmaskT, nzmask, part1, part2, cnt, out);
}